// Round 1
// baseline (342.181 us; speedup 1.0000x reference)
//
#include <hip/hip_runtime.h>
#include <math.h>

#define DIM    512
#define HEADS  8
#define DK     32
#define NKEYS  256
#define PKTOP  16
#define NTOK   1024   // b*n = 2*512

// ---------------- generic fp32 tiled GEMM ----------------
// A: [M,K] row-major. B: row-major [K,N] (BT=false) or [N,K] (BT=true).
// C[m,n] = scale * sum_k A[m,k]*B'[k,n].  grid = dim3(N/BN, M/BM), 256 thr.
template<int BM, int BN, int BK, int TM, int TN, bool BT>
__global__ __launch_bounds__(256)
void sgemm(const float* __restrict__ A, const float* __restrict__ B,
           float* __restrict__ C, int M, int N, int K, float scale)
{
    __shared__ float As[BK][BM + 4];
    __shared__ float Bs[BK][BN + 4];
    const int tid = threadIdx.x;
    const int tx  = tid & 15;
    const int ty  = tid >> 4;
    const int m0  = blockIdx.y * BM;
    const int n0  = blockIdx.x * BN;

    float acc[TM][TN];
#pragma unroll
    for (int i = 0; i < TM; ++i)
#pragma unroll
        for (int j = 0; j < TN; ++j) acc[i][j] = 0.f;

    for (int k0 = 0; k0 < K; k0 += BK) {
        // stage A tile (transposed): As[k][m] = A[m0+m][k0+k]
#pragma unroll
        for (int it = 0; it < (BM * BK / 4) / 256; ++it) {
            int L   = tid + 256 * it;
            int row = L / (BK / 4), kq = L % (BK / 4);
            float4 v = *(const float4*)(A + (size_t)(m0 + row) * K + k0 + kq * 4);
            As[kq * 4 + 0][row] = v.x; As[kq * 4 + 1][row] = v.y;
            As[kq * 4 + 2][row] = v.z; As[kq * 4 + 3][row] = v.w;
        }
        if (!BT) {
#pragma unroll
            for (int it = 0; it < (BK * BN / 4) / 256; ++it) {
                int L = tid + 256 * it;
                int k = L / (BN / 4), nq = L % (BN / 4);
                float4 v = *(const float4*)(B + (size_t)(k0 + k) * N + n0 + nq * 4);
                *(float4*)&Bs[k][nq * 4] = v;
            }
        } else {
#pragma unroll
            for (int it = 0; it < (BN * BK / 4) / 256; ++it) {
                int L = tid + 256 * it;
                int n = L / (BK / 4), kq = L % (BK / 4);
                float4 v = *(const float4*)(B + (size_t)(n0 + n) * K + k0 + kq * 4);
                Bs[kq * 4 + 0][n] = v.x; Bs[kq * 4 + 1][n] = v.y;
                Bs[kq * 4 + 2][n] = v.z; Bs[kq * 4 + 3][n] = v.w;
            }
        }
        __syncthreads();
#pragma unroll
        for (int k = 0; k < BK; ++k) {
            float a[TM], b[TN];
#pragma unroll
            for (int i = 0; i < TM; ++i) a[i] = As[k][ty * TM + i];
#pragma unroll
            for (int j = 0; j < TN; ++j) b[j] = Bs[k][tx * TN + j];
#pragma unroll
            for (int i = 0; i < TM; ++i)
#pragma unroll
                for (int j = 0; j < TN; ++j) acc[i][j] += a[i] * b[j];
        }
        __syncthreads();
    }
#pragma unroll
    for (int i = 0; i < TM; ++i)
#pragma unroll
        for (int j = 0; j < TN; ++j)
            C[(size_t)(m0 + ty * TM + i) * N + n0 + tx * TN + j] = acc[i][j] * scale;
}

// ---------------- sim + double top-16 + softmax ----------------
// pack: (monotonic float bits << 32) | (255 - idx)  -> u64 max == (max val, tie: min idx)
__device__ __forceinline__ unsigned long long packvi(float v, int idx)
{
    unsigned u = __float_as_uint(v);
    u = (u & 0x80000000u) ? ~u : (u | 0x80000000u);
    return ((unsigned long long)u << 32) | (unsigned long long)(255 - idx);
}
__device__ __forceinline__ float unpackv(unsigned long long p)
{
    unsigned u = (unsigned)(p >> 32);
    u = (u & 0x80000000u) ? (u ^ 0x80000000u) : ~u;
    return __uint_as_float(u);
}
__device__ __forceinline__ unsigned long long wmax64(unsigned long long v)
{
#pragma unroll
    for (int off = 32; off; off >>= 1) {
        unsigned long long o = __shfl_xor(v, off, 64);
        v = (o > v) ? o : v;
    }
    return v;
}

// one wave per (token, head); block = 4 waves; grid = 8192/4 = 2048
__global__ __launch_bounds__(256)
void k_simtopk(const float* __restrict__ q, const float* __restrict__ keys,
               int* __restrict__ pk_out, float* __restrict__ wt_out)
{
    const int lane = threadIdx.x & 63;
    const int th   = blockIdx.x * 4 + (threadIdx.x >> 6);   // token-head 0..8191
    const int t    = th >> 3;
    const int hh   = th & 7;

    // wave-uniform q sub-row (p=0 half): cols hh*32 .. hh*32+31
    const float4* qv = (const float4*)(q + (size_t)t * DIM + hh * DK);
    float4 qr[8];
#pragma unroll
    for (int i = 0; i < 8; ++i) qr[i] = qv[i];

    // 4 keys per lane: k = lane*4 + j ;  keys[h][k][0][d]
    unsigned long long p1[4];
#pragma unroll
    for (int j = 0; j < 4; ++j) {
        int k = lane * 4 + j;
        const float4* kv = (const float4*)(keys + ((size_t)hh * NKEYS + k) * 2 * DK);
        float s = 0.f;
#pragma unroll
        for (int i = 0; i < 8; ++i) {
            float4 kk = kv[i];
            s += kk.x * qr[i].x + kk.y * qr[i].y + kk.z * qr[i].z + kk.w * qr[i].w;
        }
        p1[j] = packvi(s, k);
    }

    // top-16 of sim (sorted desc, stable): per-lane captures for stage 2:
    //   lane l needs v0[l>>2] and i0[4*(l&3)+jj], jj=0..3
    float my_v0 = 0.f;
    int   my_i0[4] = {0, 0, 0, 0};
#pragma unroll
    for (int r = 0; r < 16; ++r) {
        unsigned long long m = p1[0];
        m = (p1[1] > m) ? p1[1] : m;
        m = (p1[2] > m) ? p1[2] : m;
        m = (p1[3] > m) ? p1[3] : m;
        m = wmax64(m);
        int   widx = 255 - (int)(m & 0xFFull);
        float wval = unpackv(m);
        if ((lane >> 2) == r)        my_v0        = wval;
        if ((lane & 3) == (r >> 2))  my_i0[r & 3] = widx;
#pragma unroll
        for (int j = 0; j < 4; ++j)
            if (widx == lane * 4 + j) p1[j] = 0ull;
    }

    // stage 2: candidate c = lane*4+jj == 16*i + j with i=l>>2, j=4*(l&3)+jj
    unsigned long long p2[4];
#pragma unroll
    for (int jj = 0; jj < 4; ++jj) {
        int c = lane * 4 + jj;
        p2[jj] = packvi(my_v0 + (float)my_i0[jj], c);
    }
    float sc0 = 0.f, ssum = 0.f, my_sc = 0.f;
    int   my_pk = 0;
#pragma unroll
    for (int r = 0; r < 16; ++r) {
        unsigned long long m = p2[0];
        m = (p2[1] > m) ? p2[1] : m;
        m = (p2[2] > m) ? p2[2] : m;
        m = (p2[3] > m) ? p2[3] : m;
        m = wmax64(m);
        int   wc   = 255 - (int)(m & 0xFFull);
        float wval = unpackv(m);
        if (r == 0) sc0 = wval;           // round 0 winner is the max
        ssum += expf(wval - sc0);
        if (lane == r) { my_sc = wval; my_pk = wc; }
#pragma unroll
        for (int j = 0; j < 4; ++j)
            if (wc == lane * 4 + j) p2[j] = 0ull;
    }
    if (lane < PKTOP) {
        int o = th * PKTOP + lane;
        pk_out[o] = my_pk;
        wt_out[o] = expf(my_sc - sc0) / ssum;
    }
}

// ---------------- gelu + softmax-weight scatter into dense C[t][e] ----------
__device__ __forceinline__ float gelu_t(float x)
{
    float x3 = x * x * x;
    return 0.5f * x * (1.f + tanhf(0.7978845608028654f * (x + 0.044715f * x3)));
}

__global__ __launch_bounds__(256)
void k_scatter(const float* __restrict__ G, const int* __restrict__ pk,
               const float* __restrict__ wt, float* __restrict__ C)
{
    __shared__ int   spk[128];
    __shared__ float swt[128];
    const int t = blockIdx.x;
    const int e = threadIdx.x;           // 0..255
    if (e < 128) { spk[e] = pk[t * 128 + e]; swt[e] = wt[t * 128 + e]; }
    __syncthreads();
    float gl  = gelu_t(G[t * 256 + e]);
    float acc = 0.f;
#pragma unroll 8
    for (int s = 0; s < 128; ++s)
        acc += (spk[s] == e) ? swt[s] : 0.f;
    C[t * 256 + e] = gl * acc;
}

// ---------------- launch ----------------
extern "C" void kernel_launch(void* const* d_in, const int* in_sizes, int n_in,
                              void* d_out, int out_size, void* d_ws, size_t ws_size,
                              hipStream_t stream)
{
    const float* x    = (const float*)d_in[0];   // [1024, 512]
    const float* wq   = (const float*)d_in[1];   // [512, 512]
    const float* keys = (const float*)d_in[2];   // [8, 256, 2, 32]
    const float* wd   = (const float*)d_in[3];   // [65536, 512] (rows 0..255 used)
    const float* wu   = (const float*)d_in[4];   // [65536, 512] (rows 0..255 used)
    float* out = (float*)d_out;                  // [1024, 512]

    float* q  = (float*)d_ws;                    // 1024*512
    float* G  = q + NTOK * DIM;                  // 1024*256
    float* C  = G + NTOK * NKEYS;                // 1024*256
    int*   pk = (int*)(C + NTOK * NKEYS);        // 1024*128
    float* wt = (float*)(pk + NTOK * 128);       // 1024*128

    const float bnscale = 1.0f / sqrtf(1.0f + 1e-5f);

    // q = (x @ wq) * bnscale          [1024 x 512], K=512
    sgemm<32, 64, 32, 2, 4, false>
        <<<dim3(DIM / 64, NTOK / 32), 256, 0, stream>>>(x, wq, q, NTOK, DIM, DIM, bnscale);

    // sim + double top-16 + softmax -> pk, wt
    k_simtopk<<<dim3(NTOK * HEADS / 4), 256, 0, stream>>>(q, keys, pk, wt);

    // G = q @ wd[0:256]^T             [1024 x 256], K=512
    sgemm<32, 32, 32, 2, 2, true>
        <<<dim3(NKEYS / 32, NTOK / 32), 256, 0, stream>>>(q, wd, G, NTOK, NKEYS, DIM, 1.0f);

    // C[t][e] = gelu(G[t][e]) * sum of softmax weights routed to e
    k_scatter<<<dim3(NTOK), 256, 0, stream>>>(G, pk, wt, C);

    // out = C @ wu[0:256]             [1024 x 512], K=256
    sgemm<32, 64, 32, 2, 4, false>
        <<<dim3(DIM / 64, NTOK / 32), 256, 0, stream>>>(C, wu, out, NTOK, DIM, NKEYS, 1.0f);
}

// Round 2
// 333.820 us; speedup vs baseline: 1.0250x; 1.0250x over previous
//
#include <hip/hip_runtime.h>
#include <math.h>

#define DIM    512
#define HEADS  8
#define DK     32
#define NKEYS  256
#define PKTOP  16
#define NTOK   1024   // b*n = 2*512

// ---------------- generic fp32 tiled GEMM ----------------
// A: [M,K] row-major. B: row-major [K,N] (BT=false) or [N,K] (BT=true).
// C[m,n] = scale * sum_k A[m,k]*B'[k,n].  grid = dim3(N/BN, M/BM), 256 thr.
template<int BM, int BN, int BK, int TM, int TN, bool BT>
__global__ __launch_bounds__(256)
void sgemm(const float* __restrict__ A, const float* __restrict__ B,
           float* __restrict__ C, int M, int N, int K, float scale)
{
    __shared__ float As[BK][BM + 4];
    __shared__ float Bs[BK][BN + 4];
    const int tid = threadIdx.x;
    const int tx  = tid & 15;
    const int ty  = tid >> 4;
    const int m0  = blockIdx.y * BM;
    const int n0  = blockIdx.x * BN;

    float acc[TM][TN];
#pragma unroll
    for (int i = 0; i < TM; ++i)
#pragma unroll
        for (int j = 0; j < TN; ++j) acc[i][j] = 0.f;

    for (int k0 = 0; k0 < K; k0 += BK) {
        // stage A tile (transposed): As[k][m] = A[m0+m][k0+k]
#pragma unroll
        for (int it = 0; it < (BM * BK / 4) / 256; ++it) {
            int L   = tid + 256 * it;
            int row = L / (BK / 4), kq = L % (BK / 4);
            float4 v = *(const float4*)(A + (size_t)(m0 + row) * K + k0 + kq * 4);
            As[kq * 4 + 0][row] = v.x; As[kq * 4 + 1][row] = v.y;
            As[kq * 4 + 2][row] = v.z; As[kq * 4 + 3][row] = v.w;
        }
        if (!BT) {
#pragma unroll
            for (int it = 0; it < (BK * BN / 4) / 256; ++it) {
                int L = tid + 256 * it;
                int k = L / (BN / 4), nq = L % (BN / 4);
                float4 v = *(const float4*)(B + (size_t)(k0 + k) * N + n0 + nq * 4);
                *(float4*)&Bs[k][nq * 4] = v;
            }
        } else {
#pragma unroll
            for (int it = 0; it < (BN * BK / 4) / 256; ++it) {
                int L = tid + 256 * it;
                int n = L / (BK / 4), kq = L % (BK / 4);
                float4 v = *(const float4*)(B + (size_t)(n0 + n) * K + k0 + kq * 4);
                Bs[kq * 4 + 0][n] = v.x; Bs[kq * 4 + 1][n] = v.y;
                Bs[kq * 4 + 2][n] = v.z; Bs[kq * 4 + 3][n] = v.w;
            }
        }
        __syncthreads();
#pragma unroll
        for (int k = 0; k < BK; ++k) {
            float a[TM], b[TN];
#pragma unroll
            for (int i = 0; i < TM; ++i) a[i] = As[k][ty * TM + i];
#pragma unroll
            for (int j = 0; j < TN; ++j) b[j] = Bs[k][tx * TN + j];
#pragma unroll
            for (int i = 0; i < TM; ++i)
#pragma unroll
                for (int j = 0; j < TN; ++j) acc[i][j] += a[i] * b[j];
        }
        __syncthreads();
    }
#pragma unroll
    for (int i = 0; i < TM; ++i)
#pragma unroll
        for (int j = 0; j < TN; ++j)
            C[(size_t)(m0 + ty * TM + i) * N + n0 + tx * TN + j] = acc[i][j] * scale;
}

// ---------------- sim + double top-16 + softmax (v2: f32 shfl + ballot) -----
// Wave-wide argmax with lax.top_k tie semantics: max value; on tie, lowest
// flat index wins. Flat index = lane*4 + slot, so "lowest lane, then lowest
// slot" == lowest index. Within-lane: strict > keeps earliest slot. Across
// lanes: __ffsll(ballot) picks lowest lane.
__global__ __launch_bounds__(256)
void k_simtopk(const float* __restrict__ q, const float* __restrict__ keys,
               int* __restrict__ pk_out, float* __restrict__ wt_out)
{
    const int lane = threadIdx.x & 63;
    const int th   = blockIdx.x * 4 + (threadIdx.x >> 6);   // token-head 0..8191
    const int t    = th >> 3;
    const int hh   = th & 7;
    const int base = lane * 4;

    // wave-uniform q sub-row (p=0 half): cols hh*32 .. hh*32+31
    const float4* qv = (const float4*)(q + (size_t)t * DIM + hh * DK);
    float4 qr[8];
#pragma unroll
    for (int i = 0; i < 8; ++i) qr[i] = qv[i];

    // 4 keys per lane: k = base + j ;  keys[h][k][0][d]
    float v1[4];
#pragma unroll
    for (int j = 0; j < 4; ++j) {
        int k = base + j;
        const float4* kv = (const float4*)(keys + ((size_t)hh * NKEYS + k) * 2 * DK);
        float s = 0.f;
#pragma unroll
        for (int i = 0; i < 8; ++i) {
            float4 kk = kv[i];
            s += kk.x * qr[i].x + kk.y * qr[i].y + kk.z * qr[i].z + kk.w * qr[i].w;
        }
        v1[j] = s;
    }

    // stage 1: top-16 of sim. Per-lane captures for stage 2:
    //   lane l needs v0[l>>2] and i0[4*(l&3)+jj], jj=0..3
    float my_v0 = 0.f;
    int   my_i0[4] = {0, 0, 0, 0};
#pragma unroll
    for (int r = 0; r < 16; ++r) {
        float b = v1[0]; int bj = 0;
        if (v1[1] > b) { b = v1[1]; bj = 1; }
        if (v1[2] > b) { b = v1[2]; bj = 2; }
        if (v1[3] > b) { b = v1[3]; bj = 3; }
        float m = b;
#pragma unroll
        for (int off = 32; off; off >>= 1) m = fmaxf(m, __shfl_xor(m, off, 64));
        unsigned long long bal = __ballot(b == m);
        int wl   = __ffsll((long long)bal) - 1;
        int widx = __shfl(base + bj, wl, 64);
        if ((lane >> 2) == r)       my_v0        = m;
        if ((lane & 3) == (r >> 2)) my_i0[r & 3] = widx;
        if (lane == wl) v1[bj] = -INFINITY;
    }

    // stage 2: candidate c = base+jj == 16*i + j with i=c>>4, j=c&15
    float v2[4];
#pragma unroll
    for (int jj = 0; jj < 4; ++jj) v2[jj] = my_v0 + (float)my_i0[jj];

    float sc0 = 0.f, ssum = 0.f, my_sc = 0.f;
    int   my_pk = 0;
#pragma unroll
    for (int r = 0; r < 16; ++r) {
        float b = v2[0]; int bj = 0;
        if (v2[1] > b) { b = v2[1]; bj = 1; }
        if (v2[2] > b) { b = v2[2]; bj = 2; }
        if (v2[3] > b) { b = v2[3]; bj = 3; }
        float m = b;
#pragma unroll
        for (int off = 32; off; off >>= 1) m = fmaxf(m, __shfl_xor(m, off, 64));
        unsigned long long bal = __ballot(b == m);
        int wl = __ffsll((long long)bal) - 1;
        int wc = __shfl(base + bj, wl, 64);
        if (r == 0) sc0 = m;              // round-0 winner is the max
        ssum += expf(m - sc0);
        if (lane == r) { my_sc = m; my_pk = wc; }
        if (lane == wl) v2[bj] = -INFINITY;
    }
    if (lane < PKTOP) {
        int o = th * PKTOP + lane;
        pk_out[o] = my_pk;
        wt_out[o] = expf(my_sc - sc0) / ssum;
    }
}

// ---------------- gelu + softmax-weight scatter into dense C[t][e] ----------
__device__ __forceinline__ float gelu_t(float x)
{
    float x3 = x * x * x;
    return 0.5f * x * (1.f + tanhf(0.7978845608028654f * (x + 0.044715f * x3)));
}

__global__ __launch_bounds__(256)
void k_scatter(const float* __restrict__ G, const int* __restrict__ pk,
               const float* __restrict__ wt, float* __restrict__ C)
{
    __shared__ int   spk[128];
    __shared__ float swt[128];
    const int t = blockIdx.x;
    const int e = threadIdx.x;           // 0..255
    if (e < 128) { spk[e] = pk[t * 128 + e]; swt[e] = wt[t * 128 + e]; }
    __syncthreads();
    float gl  = gelu_t(G[t * 256 + e]);
    float acc = 0.f;
#pragma unroll 8
    for (int s = 0; s < 128; ++s)
        acc += (spk[s] == e) ? swt[s] : 0.f;
    C[t * 256 + e] = gl * acc;
}

// ---------------- launch ----------------
extern "C" void kernel_launch(void* const* d_in, const int* in_sizes, int n_in,
                              void* d_out, int out_size, void* d_ws, size_t ws_size,
                              hipStream_t stream)
{
    const float* x    = (const float*)d_in[0];   // [1024, 512]
    const float* wq   = (const float*)d_in[1];   // [512, 512]
    const float* keys = (const float*)d_in[2];   // [8, 256, 2, 32]
    const float* wd   = (const float*)d_in[3];   // [65536, 512] (rows 0..255 used)
    const float* wu   = (const float*)d_in[4];   // [65536, 512] (rows 0..255 used)
    float* out = (float*)d_out;                  // [1024, 512]

    float* q  = (float*)d_ws;                    // 1024*512
    float* G  = q + NTOK * DIM;                  // 1024*256
    float* C  = G + NTOK * NKEYS;                // 1024*256
    int*   pk = (int*)(C + NTOK * NKEYS);        // 1024*128
    float* wt = (float*)(pk + NTOK * 128);       // 1024*128

    const float bnscale = 1.0f / sqrtf(1.0f + 1e-5f);

    // q = (x @ wq) * bnscale          [1024 x 512], K=512
    sgemm<32, 64, 64, 2, 4, false>
        <<<dim3(DIM / 64, NTOK / 32), 256, 0, stream>>>(x, wq, q, NTOK, DIM, DIM, bnscale);

    // sim + double top-16 + softmax -> pk, wt
    k_simtopk<<<dim3(NTOK * HEADS / 4), 256, 0, stream>>>(q, keys, pk, wt);

    // G = q @ wd[0:256]^T             [1024 x 256], K=512
    sgemm<32, 32, 64, 2, 2, true>
        <<<dim3(NKEYS / 32, NTOK / 32), 256, 0, stream>>>(q, wd, G, NTOK, NKEYS, DIM, 1.0f);

    // C[t][e] = gelu(G[t][e]) * sum of softmax weights routed to e
    k_scatter<<<dim3(NTOK), 256, 0, stream>>>(G, pk, wt, C);

    // out = C @ wu[0:256]             [1024 x 512], K=256
    sgemm<32, 64, 64, 2, 4, false>
        <<<dim3(DIM / 64, NTOK / 32), 256, 0, stream>>>(C, wu, out, NTOK, DIM, NKEYS, 1.0f);
}

// Round 3
// 332.616 us; speedup vs baseline: 1.0288x; 1.0036x over previous
//
#include <hip/hip_runtime.h>
#include <math.h>

#define DIM    512
#define HEADS  8
#define DK     32
#define NKEYS  256
#define PKTOP  16
#define NTOK   1024   // b*n = 2*512

// ---------------- generic fp32 tiled GEMM ----------------
// A: [M,K] row-major. B: row-major [K,N] (BT=false) or [N,K] (BT=true).
// C[m,n] = scale * sum_k A[m,k]*B'[k,n].  grid = dim3(N/BN, M/BM), 256 thr.
template<int BM, int BN, int BK, int TM, int TN, bool BT>
__global__ __launch_bounds__(256)
void sgemm(const float* __restrict__ A, const float* __restrict__ B,
           float* __restrict__ C, int M, int N, int K, float scale)
{
    __shared__ float As[BK][BM + 4];
    __shared__ float Bs[BK][BN + 4];
    const int tid = threadIdx.x;
    const int tx  = tid & 15;
    const int ty  = tid >> 4;
    const int m0  = blockIdx.y * BM;
    const int n0  = blockIdx.x * BN;

    float acc[TM][TN];
#pragma unroll
    for (int i = 0; i < TM; ++i)
#pragma unroll
        for (int j = 0; j < TN; ++j) acc[i][j] = 0.f;

    for (int k0 = 0; k0 < K; k0 += BK) {
        // stage A tile (transposed): As[k][m] = A[m0+m][k0+k]
#pragma unroll
        for (int it = 0; it < (BM * BK / 4) / 256; ++it) {
            int L   = tid + 256 * it;
            int row = L / (BK / 4), kq = L % (BK / 4);
            float4 v = *(const float4*)(A + (size_t)(m0 + row) * K + k0 + kq * 4);
            As[kq * 4 + 0][row] = v.x; As[kq * 4 + 1][row] = v.y;
            As[kq * 4 + 2][row] = v.z; As[kq * 4 + 3][row] = v.w;
        }
        if (!BT) {
#pragma unroll
            for (int it = 0; it < (BK * BN / 4) / 256; ++it) {
                int L = tid + 256 * it;
                int k = L / (BN / 4), nq = L % (BN / 4);
                float4 v = *(const float4*)(B + (size_t)(k0 + k) * N + n0 + nq * 4);
                *(float4*)&Bs[k][nq * 4] = v;
            }
        } else {
#pragma unroll
            for (int it = 0; it < (BN * BK / 4) / 256; ++it) {
                int L = tid + 256 * it;
                int n = L / (BK / 4), kq = L % (BK / 4);
                float4 v = *(const float4*)(B + (size_t)(n0 + n) * K + k0 + kq * 4);
                Bs[kq * 4 + 0][n] = v.x; Bs[kq * 4 + 1][n] = v.y;
                Bs[kq * 4 + 2][n] = v.z; Bs[kq * 4 + 3][n] = v.w;
            }
        }
        __syncthreads();
#pragma unroll
        for (int k = 0; k < BK; ++k) {
            float a[TM], b[TN];
#pragma unroll
            for (int i = 0; i < TM; ++i) a[i] = As[k][ty * TM + i];
#pragma unroll
            for (int j = 0; j < TN; ++j) b[j] = Bs[k][tx * TN + j];
#pragma unroll
            for (int i = 0; i < TM; ++i)
#pragma unroll
                for (int j = 0; j < TN; ++j) acc[i][j] += a[i] * b[j];
        }
        __syncthreads();
    }
#pragma unroll
    for (int i = 0; i < TM; ++i)
#pragma unroll
        for (int j = 0; j < TN; ++j)
            C[(size_t)(m0 + ty * TM + i) * N + n0 + tx * TN + j] = acc[i][j] * scale;
}

// ---------------- sim + double top-16 + softmax (f32 shfl + ballot) ---------
// Wave-wide argmax with lax.top_k tie semantics: max value; on tie, lowest
// flat index wins. Flat index = lane*4 + slot, so "lowest lane, then lowest
// slot" == lowest index. Within-lane: strict > keeps earliest slot. Across
// lanes: __ffsll(ballot) picks lowest lane.
__global__ __launch_bounds__(256)
void k_simtopk(const float* __restrict__ q, const float* __restrict__ keys,
               int* __restrict__ pk_out, float* __restrict__ wt_out)
{
    const int lane = threadIdx.x & 63;
    const int th   = blockIdx.x * 4 + (threadIdx.x >> 6);   // token-head 0..8191
    const int t    = th >> 3;
    const int hh   = th & 7;
    const int base = lane * 4;

    // wave-uniform q sub-row (p=0 half): cols hh*32 .. hh*32+31
    const float4* qv = (const float4*)(q + (size_t)t * DIM + hh * DK);
    float4 qr[8];
#pragma unroll
    for (int i = 0; i < 8; ++i) qr[i] = qv[i];

    // 4 keys per lane: k = base + j ;  keys[h][k][0][d]
    float v1[4];
#pragma unroll
    for (int j = 0; j < 4; ++j) {
        int k = base + j;
        const float4* kv = (const float4*)(keys + ((size_t)hh * NKEYS + k) * 2 * DK);
        float s = 0.f;
#pragma unroll
        for (int i = 0; i < 8; ++i) {
            float4 kk = kv[i];
            s += kk.x * qr[i].x + kk.y * qr[i].y + kk.z * qr[i].z + kk.w * qr[i].w;
        }
        v1[j] = s;
    }

    // stage 1: top-16 of sim. Per-lane captures for stage 2:
    //   lane l needs v0[l>>2] and i0[4*(l&3)+jj], jj=0..3
    float my_v0 = 0.f;
    int   my_i0[4] = {0, 0, 0, 0};
#pragma unroll
    for (int r = 0; r < 16; ++r) {
        float b = v1[0]; int bj = 0;
        if (v1[1] > b) { b = v1[1]; bj = 1; }
        if (v1[2] > b) { b = v1[2]; bj = 2; }
        if (v1[3] > b) { b = v1[3]; bj = 3; }
        float m = b;
#pragma unroll
        for (int off = 32; off; off >>= 1) m = fmaxf(m, __shfl_xor(m, off, 64));
        unsigned long long bal = __ballot(b == m);
        int wl   = __ffsll((long long)bal) - 1;
        int widx = __shfl(base + bj, wl, 64);
        if ((lane >> 2) == r)       my_v0        = m;
        if ((lane & 3) == (r >> 2)) my_i0[r & 3] = widx;
        if (lane == wl) v1[bj] = -INFINITY;
    }

    // stage 2: candidate c = base+jj == 16*i + j with i=c>>4, j=c&15
    float v2[4];
#pragma unroll
    for (int jj = 0; jj < 4; ++jj) v2[jj] = my_v0 + (float)my_i0[jj];

    float sc0 = 0.f, ssum = 0.f, my_sc = 0.f;
    int   my_pk = 0;
#pragma unroll
    for (int r = 0; r < 16; ++r) {
        float b = v2[0]; int bj = 0;
        if (v2[1] > b) { b = v2[1]; bj = 1; }
        if (v2[2] > b) { b = v2[2]; bj = 2; }
        if (v2[3] > b) { b = v2[3]; bj = 3; }
        float m = b;
#pragma unroll
        for (int off = 32; off; off >>= 1) m = fmaxf(m, __shfl_xor(m, off, 64));
        unsigned long long bal = __ballot(b == m);
        int wl = __ffsll((long long)bal) - 1;
        int wc = __shfl(base + bj, wl, 64);
        if (r == 0) sc0 = m;              // round-0 winner is the max
        ssum += expf(m - sc0);
        if (lane == r) { my_sc = m; my_pk = wc; }
        if (lane == wl) v2[bj] = -INFINITY;
    }
    if (lane < PKTOP) {
        int o = th * PKTOP + lane;
        pk_out[o] = my_pk;
        wt_out[o] = expf(my_sc - sc0) / ssum;
    }
}

// ---------------- fused G-GEMM + gelu*wsum scatter epilogue -----------------
// G[t,e] = q[t,:] . wd[e,:]  (32x32 tile, K=512, B transposed),
// C[t,e] = gelu(G) * sum_{s: pk[t,s]==e} wt[t,s]   written directly.
__device__ __forceinline__ float gelu_t(float x)
{
    float x3 = x * x * x;
    return 0.5f * x * (1.f + tanhf(0.7978845608028654f * (x + 0.044715f * x3)));
}

#define GBM 32
#define GBN 32
#define GBK 64

__global__ __launch_bounds__(256)
void k_gemm_scatter(const float* __restrict__ A, const float* __restrict__ B,
                    const int* __restrict__ pk, const float* __restrict__ wt,
                    float* __restrict__ C)
{
    __shared__ float As[GBK][GBM + 4];
    __shared__ float Bs[GBK][GBN + 4];
    __shared__ float wsum[GBM][GBN + 1];
    const int tid = threadIdx.x;
    const int tx  = tid & 15;
    const int ty  = tid >> 4;
    const int m0  = blockIdx.y * GBM;   // token base
    const int n0  = blockIdx.x * GBN;   // expert base

    // zero block-local wsum
    for (int i = tid; i < GBM * (GBN + 1); i += 256)
        ((float*)wsum)[i] = 0.f;
    __syncthreads();
    // scatter this block's expert slice: 32 tokens x 128 (head,slot) entries
    for (int i = tid; i < GBM * 128; i += 256) {
        int tok = i >> 7, s = i & 127;
        int e = pk[(size_t)(m0 + tok) * 128 + s];
        if (e >= n0 && e < n0 + GBN)
            atomicAdd(&wsum[tok][e - n0], wt[(size_t)(m0 + tok) * 128 + s]);
    }

    float acc[2][2] = {{0.f, 0.f}, {0.f, 0.f}};
    const int K = DIM;
    for (int k0 = 0; k0 < K; k0 += GBK) {
        // A tile (transposed): As[k][m] = A[m0+m][k0+k]
#pragma unroll
        for (int it = 0; it < (GBM * GBK / 4) / 256; ++it) {
            int L   = tid + 256 * it;
            int row = L / (GBK / 4), kq = L % (GBK / 4);
            float4 v = *(const float4*)(A + (size_t)(m0 + row) * K + k0 + kq * 4);
            As[kq * 4 + 0][row] = v.x; As[kq * 4 + 1][row] = v.y;
            As[kq * 4 + 2][row] = v.z; As[kq * 4 + 3][row] = v.w;
        }
        // B tile (B is [N,K] row-major): Bs[k][n] = B[n0+n][k0+k]
#pragma unroll
        for (int it = 0; it < (GBN * GBK / 4) / 256; ++it) {
            int L = tid + 256 * it;
            int n = L / (GBK / 4), kq = L % (GBK / 4);
            float4 v = *(const float4*)(B + (size_t)(n0 + n) * K + k0 + kq * 4);
            Bs[kq * 4 + 0][n] = v.x; Bs[kq * 4 + 1][n] = v.y;
            Bs[kq * 4 + 2][n] = v.z; Bs[kq * 4 + 3][n] = v.w;
        }
        __syncthreads();
#pragma unroll
        for (int k = 0; k < GBK; ++k) {
            float a0 = As[k][ty * 2], a1 = As[k][ty * 2 + 1];
            float b0 = Bs[k][tx * 2], b1 = Bs[k][tx * 2 + 1];
            acc[0][0] += a0 * b0; acc[0][1] += a0 * b1;
            acc[1][0] += a1 * b0; acc[1][1] += a1 * b1;
        }
        __syncthreads();
    }
#pragma unroll
    for (int i = 0; i < 2; ++i)
#pragma unroll
        for (int j = 0; j < 2; ++j) {
            int tok = ty * 2 + i, e = tx * 2 + j;
            C[(size_t)(m0 + tok) * NKEYS + n0 + e] =
                gelu_t(acc[i][j]) * wsum[tok][e];
        }
}

// ---------------- launch ----------------
extern "C" void kernel_launch(void* const* d_in, const int* in_sizes, int n_in,
                              void* d_out, int out_size, void* d_ws, size_t ws_size,
                              hipStream_t stream)
{
    const float* x    = (const float*)d_in[0];   // [1024, 512]
    const float* wq   = (const float*)d_in[1];   // [512, 512]
    const float* keys = (const float*)d_in[2];   // [8, 256, 2, 32]
    const float* wd   = (const float*)d_in[3];   // [65536, 512] (rows 0..255 used)
    const float* wu   = (const float*)d_in[4];   // [65536, 512] (rows 0..255 used)
    float* out = (float*)d_out;                  // [1024, 512]

    float* q  = (float*)d_ws;                    // 1024*512
    float* C  = q + NTOK * DIM;                  // 1024*256
    int*   pk = (int*)(C + NTOK * NKEYS);        // 1024*128
    float* wt = (float*)(pk + NTOK * 128);       // 1024*128

    const float bnscale = 1.0f / sqrtf(1.0f + 1e-5f);

    // q = (x @ wq) * bnscale          [1024 x 512], K=512
    sgemm<32, 64, 64, 2, 4, false>
        <<<dim3(DIM / 64, NTOK / 32), 256, 0, stream>>>(x, wq, q, NTOK, DIM, DIM, bnscale);

    // sim + double top-16 + softmax -> pk, wt
    k_simtopk<<<dim3(NTOK * HEADS / 4), 256, 0, stream>>>(q, keys, pk, wt);

    // C[t,e] = gelu(q . wd[e]) * routed-softmax-weight   [1024 x 256], K=512
    k_gemm_scatter<<<dim3(NKEYS / GBN, NTOK / GBM), 256, 0, stream>>>(q, wd, pk, wt, C);

    // out = C @ wu[0:256]             [1024 x 512], K=256
    sgemm<32, 64, 64, 2, 4, false>
        <<<dim3(DIM / 64, NTOK / 32), 256, 0, stream>>>(C, wu, out, NTOK, DIM, NKEYS, 1.0f);
}